// Round 1
// baseline (385.256 us; speedup 1.0000x reference)
//
#include <hip/hip_runtime.h>

typedef _Float16 f16;
typedef _Float16 f16x4 __attribute__((ext_vector_type(4)));
typedef _Float16 f16x8 __attribute__((ext_vector_type(8)));
typedef float f32x4 __attribute__((ext_vector_type(4)));

#define DEVINL __device__ __forceinline__

// async global->LDS, 16B per lane. LDS dest must be uniform-base + lane*16.
DEVINL void gload16(const void* g, void* l) {
    __builtin_amdgcn_global_load_lds(
        (const __attribute__((address_space(1))) unsigned int*)g,
        (__attribute__((address_space(3))) unsigned int*)l, 16, 0, 0);
}

// ---------------------------------------------------------------- convert
__global__ __launch_bounds__(256) void cvt_kernel(const float* __restrict__ in,
                                                  f16* __restrict__ out, int n4) {
    int i = blockIdx.x * 256 + threadIdx.x;
    int st = gridDim.x * 256;
    for (; i < n4; i += st) {
        float4 v = reinterpret_cast<const float4*>(in)[i];
        f16x4 o = {(f16)v.x, (f16)v.y, (f16)v.z, (f16)v.w};
        reinterpret_cast<f16x4*>(out)[i] = o;
    }
}

// ---------------------------------------------------------------- GEMM C = A * B^T (+bias)
// A[M,1024] fp16 row-major, B[N,1024] fp16 row-major (contract over K=1024).
// 128x128 tile, BK=32, 256 thr (4 waves, 2x2), 2-phase global_load_lds dbuf.
// EPI=0: in_proj epilogue -> scatter Q[b,h,s,d], K[b,h,s,d], Vt[b,h,d,s] fp16
// EPI=1: out_proj epilogue -> f32 Cout[M,1024] + bias
template <int EPI>
__global__ __launch_bounds__(256) void gemm_bt(
    const f16* __restrict__ A, const f16* __restrict__ Bm,
    const float* __restrict__ bias, float* __restrict__ Cout,
    f16* __restrict__ Qw, f16* __restrict__ Kw, f16* __restrict__ Vtw) {
    constexpr int K = 1024, NT = K / 32;
    __shared__ f16 As[2][128 * 32];
    __shared__ f16 Bs[2][128 * 32];
    const int t = threadIdx.x;
    const int wave = t >> 6, lane = t & 63, lr = lane & 15, lg = lane >> 4;
    const int wr = wave >> 1, wc = wave & 1;
    const int m0 = blockIdx.y * 128, n0 = blockIdx.x * 128;

    const f16* Ag = A + (m0 + (t >> 2)) * K + (t & 3) * 8;
    const f16* Bg = Bm + (n0 + (t >> 2)) * K + (t & 3) * 8;

    f32x4 acc[4][4] = {};

    auto stage = [&](int buf, int kt) {
        const f16* a = Ag + kt * 32;
        const f16* b = Bg + kt * 32;
        f16* al = &As[buf][t * 8];
        f16* bl = &Bs[buf][t * 8];
        gload16(a, al);
        gload16(a + 64 * K, al + 64 * 32);
        gload16(b, bl);
        gload16(b + 64 * K, bl + 64 * 32);
    };

    stage(0, 0);
    __syncthreads();
    int cur = 0;
    for (int kt = 0; kt < NT; ++kt) {
        if (kt + 1 < NT) stage(cur ^ 1, kt + 1);
        const f16* as = &As[cur][0];
        const f16* bs = &Bs[cur][0];
        f16x8 af[4], bf[4];
#pragma unroll
        for (int i = 0; i < 4; ++i)
            af[i] = *(const f16x8*)&as[(wr * 64 + i * 16 + lr) * 32 + lg * 8];
#pragma unroll
        for (int i = 0; i < 4; ++i)
            bf[i] = *(const f16x8*)&bs[(wc * 64 + i * 16 + lr) * 32 + lg * 8];
#pragma unroll
        for (int i = 0; i < 4; ++i)
#pragma unroll
            for (int j = 0; j < 4; ++j)
                acc[i][j] = __builtin_amdgcn_mfma_f32_16x16x32_f16(af[i], bf[j], acc[i][j], 0, 0, 0);
        __syncthreads();
        cur ^= 1;
    }

    // epilogue. C[m][n]: m = m0 + wr*64 + mf*16 + lg*4 + r ; n = n0 + wc*64 + nf*16 + lr
    if constexpr (EPI == 0) {
#pragma unroll
        for (int nf = 0; nf < 4; ++nf) {
            int n = n0 + wc * 64 + nf * 16 + lr;
            float bv = bias[n];
            int part = n >> 10, e = n & 1023, hh = e >> 6, dd = e & 63;
#pragma unroll
            for (int mf = 0; mf < 4; ++mf) {
                int m = m0 + wr * 64 + mf * 16 + lg * 4;
                int bb = m >> 10, ss = m & 1023;
                if (part == 0) {
                    f16* dst = Qw + ((bb * 16 + hh) * 1024 + ss) * 64 + dd;
#pragma unroll
                    for (int r = 0; r < 4; ++r) dst[r * 64] = (f16)(acc[mf][nf][r] + bv);
                } else if (part == 1) {
                    f16* dst = Kw + ((bb * 16 + hh) * 1024 + ss) * 64 + dd;
#pragma unroll
                    for (int r = 0; r < 4; ++r) dst[r * 64] = (f16)(acc[mf][nf][r] + bv);
                } else {
                    f16x4 pk;
#pragma unroll
                    for (int r = 0; r < 4; ++r) pk[r] = (f16)(acc[mf][nf][r] + bv);
                    *(f16x4*)(Vtw + ((bb * 16 + hh) * 64 + dd) * 1024 + ss) = pk;
                }
            }
        }
    } else {
#pragma unroll
        for (int nf = 0; nf < 4; ++nf) {
            int n = n0 + wc * 64 + nf * 16 + lr;
            float bv = bias[n];
#pragma unroll
            for (int mf = 0; mf < 4; ++mf) {
                int m = m0 + wr * 64 + mf * 16 + lg * 4;
#pragma unroll
                for (int r = 0; r < 4; ++r) Cout[(m + r) * 1024 + n] = acc[mf][nf][r] + bv;
            }
        }
    }
}

// ---------------------------------------------------------------- flash attention
// grid (8 qtiles, 16 heads, 8 batch), 256 thr. Per wave: 32 q-rows.
// KVBLK=64, K tile [64kk][64d], V tile [64d][64kk] (from pre-transposed Vt),
// both XOR-swizzled (byte ^= (row&7)<<4) via pre-swizzled global source.
__global__ __launch_bounds__(256) void attn_kernel(const f16* __restrict__ Qw,
                                                   const f16* __restrict__ Kw,
                                                   const f16* __restrict__ Vtw,
                                                   f16* __restrict__ AO) {
    __shared__ f16 Ksm[2][64 * 64];
    __shared__ f16 Vsm[2][64 * 64];
    __shared__ f16 Ps[4][32 * 64];
    const int t = threadIdx.x, wave = t >> 6, lane = t & 63, lr = lane & 15, lg = lane >> 4;
    const int b = blockIdx.z, h = blockIdx.y, qt = blockIdx.x;
    const f16* Qp = Qw + (b * 16 + h) * 1024 * 64;
    const f16* Kp = Kw + (b * 16 + h) * 1024 * 64;
    const f16* Vp = Vtw + (b * 16 + h) * 64 * 1024;
    const int q0 = qt * 128 + wave * 32;

    // hoist Q fragments (A-operand): row=q0+fq*16+lr, k = dh*32 + lg*8 + [0..8)
    f16x8 qf[2][2];
#pragma unroll
    for (int fq = 0; fq < 2; ++fq)
#pragma unroll
        for (int dh = 0; dh < 2; ++dh)
            qf[fq][dh] = *(const f16x8*)&Qp[(q0 + fq * 16 + lr) * 64 + dh * 32 + lg * 8];

    auto stage_kv = [&](int buf, int kv) {
#pragma unroll
        for (int c = 0; c < 2; ++c) {
            int row = c * 32 + (t >> 3);
            int w = (t & 7) << 4;               // byte within 128-B row
            int gw = w ^ ((row & 7) << 4);      // pre-swizzle the SOURCE (rule 21)
            gload16((const char*)(Kp + (kv + row) * 64) + gw,
                    (char*)&Ksm[buf][0] + c * 4096 + t * 16);
            gload16((const char*)(Vp + row * 1024 + kv) + gw,
                    (char*)&Vsm[buf][0] + c * 4096 + t * 16);
        }
    };

    f32x4 o[2][4] = {};
    float mrow[2][4], lsum[2][4];
#pragma unroll
    for (int fq = 0; fq < 2; ++fq)
#pragma unroll
        for (int r = 0; r < 4; ++r) { mrow[fq][r] = -1e30f; lsum[fq][r] = 0.f; }

    stage_kv(0, 0);
    __syncthreads();
    int cur = 0;
    const float SC = 0.125f * 1.44269504088896f;  // 1/sqrt(64) * log2(e)

    for (int kv = 0; kv < 16; ++kv) {
        if (kv + 1 < 16) stage_kv(cur ^ 1, (kv + 1) * 64);

        // ---- QK^T: S[q][kk] = sum_d Q[q][d] K[kk][d]
        f32x4 s[2][4] = {};
#pragma unroll
        for (int dh = 0; dh < 2; ++dh) {
            f16x8 kfr[4];
#pragma unroll
            for (int kf = 0; kf < 4; ++kf) {
                int row = kf * 16 + lr;
                int byt = dh * 64 + lg * 16;
                kfr[kf] = *(const f16x8*)((const char*)&Ksm[cur][0] + row * 128 +
                                          (byt ^ ((row & 7) << 4)));
            }
#pragma unroll
            for (int fq = 0; fq < 2; ++fq)
#pragma unroll
                for (int kf = 0; kf < 4; ++kf)
                    s[fq][kf] = __builtin_amdgcn_mfma_f32_16x16x32_f16(qf[fq][dh], kfr[kf],
                                                                       s[fq][kf], 0, 0, 0);
        }

        // ---- online softmax (rows = lg*4 + r per fq; cols = 4 kf frags x 16 lanes)
#pragma unroll
        for (int fq = 0; fq < 2; ++fq) {
            f32x4 ts[4];
#pragma unroll
            for (int kf = 0; kf < 4; ++kf) ts[kf] = s[fq][kf] * SC;
#pragma unroll
            for (int r = 0; r < 4; ++r) {
                float v = fmaxf(fmaxf(ts[0][r], ts[1][r]), fmaxf(ts[2][r], ts[3][r]));
                v = fmaxf(v, __shfl_xor(v, 1, 16));
                v = fmaxf(v, __shfl_xor(v, 2, 16));
                v = fmaxf(v, __shfl_xor(v, 4, 16));
                v = fmaxf(v, __shfl_xor(v, 8, 16));
                float mn = fmaxf(mrow[fq][r], v);
                float al = exp2f(mrow[fq][r] - mn);
                mrow[fq][r] = mn;
                float ps = 0.f;
                int q = fq * 16 + lg * 4 + r;
#pragma unroll
                for (int kf = 0; kf < 4; ++kf) {
                    float p = exp2f(ts[kf][r] - mn);
                    ps += p;
                    int kkb = (kf * 16 + lr) * 2;
                    *(f16*)((char*)&Ps[wave][0] + q * 128 + (kkb ^ ((q & 7) << 4))) = (f16)p;
                }
                ps += __shfl_xor(ps, 1, 16);
                ps += __shfl_xor(ps, 2, 16);
                ps += __shfl_xor(ps, 4, 16);
                ps += __shfl_xor(ps, 8, 16);
                lsum[fq][r] = lsum[fq][r] * al + ps;
#pragma unroll
                for (int df = 0; df < 4; ++df) o[fq][df][r] *= al;
            }
        }

        // ---- PV: O[q][d] += sum_kk P[q][kk] V[kk][d]
#pragma unroll
        for (int ks = 0; ks < 2; ++ks) {
            f16x8 pa[2], vb[4];
#pragma unroll
            for (int fq = 0; fq < 2; ++fq) {
                int row = fq * 16 + lr;
                int byt = ks * 64 + lg * 16;
                pa[fq] = *(const f16x8*)((const char*)&Ps[wave][0] + row * 128 +
                                         (byt ^ ((row & 7) << 4)));
            }
#pragma unroll
            for (int df = 0; df < 4; ++df) {
                int row = df * 16 + lr;
                int byt = ks * 64 + lg * 16;
                vb[df] = *(const f16x8*)((const char*)&Vsm[cur][0] + row * 128 +
                                         (byt ^ ((row & 7) << 4)));
            }
#pragma unroll
            for (int fq = 0; fq < 2; ++fq)
#pragma unroll
                for (int df = 0; df < 4; ++df)
                    o[fq][df] = __builtin_amdgcn_mfma_f32_16x16x32_f16(pa[fq], vb[df],
                                                                      o[fq][df], 0, 0, 0);
        }
        __syncthreads();
        cur ^= 1;
    }

    // ---- normalize + write AO[b*1024+s][h*64+d] fp16
#pragma unroll
    for (int fq = 0; fq < 2; ++fq) {
#pragma unroll
        for (int r = 0; r < 4; ++r) {
            float inv = 1.0f / lsum[fq][r];
            int ss = q0 + fq * 16 + lg * 4 + r;
#pragma unroll
            for (int df = 0; df < 4; ++df) {
                int d = df * 16 + lr;
                AO[(b * 1024 + ss) * 1024 + h * 64 + d] = (f16)(o[fq][df][r] * inv);
            }
        }
    }
}

// ---------------------------------------------------------------- launch
extern "C" void kernel_launch(void* const* d_in, const int* in_sizes, int n_in,
                              void* d_out, int out_size, void* d_ws, size_t ws_size,
                              hipStream_t stream) {
    const float* qkv = (const float*)d_in[0];
    const float* w_in = (const float*)d_in[1];
    const float* b_in = (const float*)d_in[2];
    const float* w_out = (const float*)d_in[3];
    const float* b_out = (const float*)d_in[4];
    float* out = (float*)d_out;

    // workspace carve (fp16 elems). AO aliases Xh (in_proj done before attn writes AO).
    f16* Xh = (f16*)d_ws;            // 8192*1024
    f16* Wih = Xh + 8388608;         // 3072*1024
    f16* Woh = Wih + 3145728;        // 1024*1024
    f16* Qw = Woh + 1048576;         // [8][16][1024][64]
    f16* Kw = Qw + 8388608;          // [8][16][1024][64]
    f16* Vtw = Kw + 8388608;         // [8][16][64][1024]  (transposed V)
    f16* AO = Xh;

    cvt_kernel<<<2048, 256, 0, stream>>>(qkv, Xh, 8388608 / 4);
    cvt_kernel<<<1024, 256, 0, stream>>>(w_in, Wih, 3145728 / 4);
    cvt_kernel<<<512, 256, 0, stream>>>(w_out, Woh, 1048576 / 4);

    gemm_bt<0><<<dim3(24, 64), 256, 0, stream>>>(Xh, Wih, b_in, nullptr, Qw, Kw, Vtw);
    attn_kernel<<<dim3(8, 16, 8), 256, 0, stream>>>(Qw, Kw, Vtw, AO);
    gemm_bt<1><<<dim3(8, 64), 256, 0, stream>>>(AO, Woh, b_out, out, nullptr, nullptr, nullptr);
}

// Round 2
// 298.706 us; speedup vs baseline: 1.2898x; 1.2898x over previous
//
#include <hip/hip_runtime.h>

typedef _Float16 f16;
typedef _Float16 f16x4 __attribute__((ext_vector_type(4)));
typedef _Float16 f16x8 __attribute__((ext_vector_type(8)));
typedef float f32x4 __attribute__((ext_vector_type(4)));
typedef float f32x16 __attribute__((ext_vector_type(16)));
typedef unsigned u32x4 __attribute__((ext_vector_type(4)));

#define DEVINL __device__ __forceinline__

// async global->LDS, 16B per lane. LDS dest must be uniform-base + lane*16.
DEVINL void gload16(const void* g, void* l) {
    __builtin_amdgcn_global_load_lds(
        (const __attribute__((address_space(1))) unsigned int*)g,
        (__attribute__((address_space(3))) unsigned int*)l, 16, 0, 0);
}

DEVINL unsigned pk2(float a, float b) {
    auto v = __builtin_amdgcn_cvt_pkrtz(a, b);  // v_cvt_pkrtz_f16_f32
    return __builtin_bit_cast(unsigned, v);
}

// ---------------------------------------------------------------- convert
__global__ __launch_bounds__(256) void cvt_kernel(const float* __restrict__ in,
                                                  f16* __restrict__ out, int n4) {
    int i = blockIdx.x * 256 + threadIdx.x;
    int st = gridDim.x * 256;
    for (; i < n4; i += st) {
        float4 v = reinterpret_cast<const float4*>(in)[i];
        f16x4 o = {(f16)v.x, (f16)v.y, (f16)v.z, (f16)v.w};
        reinterpret_cast<f16x4*>(out)[i] = o;
    }
}

// ---------------------------------------------------------------- GEMM C = A * B^T (+bias)
// (unchanged from round 1 — passed)
template <int EPI>
__global__ __launch_bounds__(256) void gemm_bt(
    const f16* __restrict__ A, const f16* __restrict__ Bm,
    const float* __restrict__ bias, float* __restrict__ Cout,
    f16* __restrict__ Qw, f16* __restrict__ Kw, f16* __restrict__ Vtw) {
    constexpr int K = 1024, NT = K / 32;
    __shared__ f16 As[2][128 * 32];
    __shared__ f16 Bs[2][128 * 32];
    const int t = threadIdx.x;
    const int wave = t >> 6, lane = t & 63, lr = lane & 15, lg = lane >> 4;
    const int wr = wave >> 1, wc = wave & 1;
    const int m0 = blockIdx.y * 128, n0 = blockIdx.x * 128;

    const f16* Ag = A + (m0 + (t >> 2)) * K + (t & 3) * 8;
    const f16* Bg = Bm + (n0 + (t >> 2)) * K + (t & 3) * 8;

    f32x4 acc[4][4] = {};

    auto stage = [&](int buf, int kt) {
        const f16* a = Ag + kt * 32;
        const f16* b = Bg + kt * 32;
        f16* al = &As[buf][t * 8];
        f16* bl = &Bs[buf][t * 8];
        gload16(a, al);
        gload16(a + 64 * K, al + 64 * 32);
        gload16(b, bl);
        gload16(b + 64 * K, bl + 64 * 32);
    };

    stage(0, 0);
    __syncthreads();
    int cur = 0;
    for (int kt = 0; kt < NT; ++kt) {
        if (kt + 1 < NT) stage(cur ^ 1, kt + 1);
        const f16* as = &As[cur][0];
        const f16* bs = &Bs[cur][0];
        f16x8 af[4], bf[4];
#pragma unroll
        for (int i = 0; i < 4; ++i)
            af[i] = *(const f16x8*)&as[(wr * 64 + i * 16 + lr) * 32 + lg * 8];
#pragma unroll
        for (int i = 0; i < 4; ++i)
            bf[i] = *(const f16x8*)&bs[(wc * 64 + i * 16 + lr) * 32 + lg * 8];
#pragma unroll
        for (int i = 0; i < 4; ++i)
#pragma unroll
            for (int j = 0; j < 4; ++j)
                acc[i][j] = __builtin_amdgcn_mfma_f32_16x16x32_f16(af[i], bf[j], acc[i][j], 0, 0, 0);
        __syncthreads();
        cur ^= 1;
    }

    if constexpr (EPI == 0) {
#pragma unroll
        for (int nf = 0; nf < 4; ++nf) {
            int n = n0 + wc * 64 + nf * 16 + lr;
            float bv = bias[n];
            int part = n >> 10, e = n & 1023, hh = e >> 6, dd = e & 63;
#pragma unroll
            for (int mf = 0; mf < 4; ++mf) {
                int m = m0 + wr * 64 + mf * 16 + lg * 4;
                int bb = m >> 10, ss = m & 1023;
                if (part == 0) {
                    f16* dst = Qw + ((bb * 16 + hh) * 1024 + ss) * 64 + dd;
#pragma unroll
                    for (int r = 0; r < 4; ++r) dst[r * 64] = (f16)(acc[mf][nf][r] + bv);
                } else if (part == 1) {
                    f16* dst = Kw + ((bb * 16 + hh) * 1024 + ss) * 64 + dd;
#pragma unroll
                    for (int r = 0; r < 4; ++r) dst[r * 64] = (f16)(acc[mf][nf][r] + bv);
                } else {
                    f16x4 pkv;
#pragma unroll
                    for (int r = 0; r < 4; ++r) pkv[r] = (f16)(acc[mf][nf][r] + bv);
                    *(f16x4*)(Vtw + ((bb * 16 + hh) * 64 + dd) * 1024 + ss) = pkv;
                }
            }
        }
    } else {
#pragma unroll
        for (int nf = 0; nf < 4; ++nf) {
            int n = n0 + wc * 64 + nf * 16 + lr;
            float bv = bias[n];
#pragma unroll
            for (int mf = 0; mf < 4; ++mf) {
                int m = m0 + wr * 64 + mf * 16 + lg * 4;
#pragma unroll
                for (int r = 0; r < 4; ++r) Cout[(m + r) * 1024 + n] = acc[mf][nf][r] + bv;
            }
        }
    }
}

// ---------------------------------------------------------------- flash attention (swapped, 32x32)
// grid (8 qtiles, 16 heads, 8 batch), 256 thr = 4 waves x 32 q-rows.
// S^T = mfma_32x32x16(K, Q): lane holds q = lane&31 (lane-local softmax).
// O^T = mfma_32x32x16(Vt, P^T): rescale lane-local. P^T B-frags built in-register
// via cvt_pkrtz + shfl_xor(32). K/V tiles [64][64] f16 in LDS, XOR-swizzled
// (byte ^= (row&7)<<4) with pre-swizzled global source (both-sides rule).
__global__ __launch_bounds__(256) void attn_kernel(const f16* __restrict__ Qw,
                                                   const f16* __restrict__ Kw,
                                                   const f16* __restrict__ Vtw,
                                                   f16* __restrict__ AO) {
    __shared__ f16 Ksm[2][64 * 64];
    __shared__ f16 Vsm[2][64 * 64];
    const int t = threadIdx.x, wave = t >> 6, lane = t & 63;
    const int ql = lane & 31, hi = lane >> 5;
    const int b = blockIdx.z, h = blockIdx.y, qt = blockIdx.x;
    const f16* Qp = Qw + (b * 16 + h) * 1024 * 64;
    const f16* Kp = Kw + (b * 16 + h) * 1024 * 64;
    const f16* Vp = Vtw + (b * 16 + h) * 64 * 1024;
    const int q0 = qt * 128 + wave * 32;

    // Q as B-operand: qb[s] holds Q[q0+ql][s*16 + hi*8 + j]  (k = d)
    f16x8 qb[4];
#pragma unroll
    for (int s = 0; s < 4; ++s)
        qb[s] = *(const f16x8*)&Qp[(q0 + ql) * 64 + s * 16 + hi * 8];

    auto stage_kv = [&](int buf, int kv) {
#pragma unroll
        for (int c = 0; c < 2; ++c) {
            int row = c * 32 + (t >> 3);
            int w = (t & 7) << 4;
            int gw = w ^ ((row & 7) << 4);  // pre-swizzle SOURCE (rule 21)
            gload16((const char*)(Kp + (kv + row) * 64) + gw,
                    (char*)&Ksm[buf][0] + c * 4096 + t * 16);
            gload16((const char*)(Vp + row * 1024 + kv) + gw,
                    (char*)&Vsm[buf][0] + c * 4096 + t * 16);
        }
    };

    f32x16 o0 = 0.f, o1 = 0.f;
    float mraw = -1e30f, lsum = 0.f;
    const float SC = 0.125f * 1.44269504088896f;  // 1/sqrt(64) * log2(e)

    stage_kv(0, 0);
    __syncthreads();
    int cur = 0;

    for (int kv = 0; kv < 16; ++kv) {
        if (kv + 1 < 16) stage_kv(cur ^ 1, (kv + 1) * 64);
        const char* Kb = (const char*)&Ksm[cur][0];
        const char* Vb = (const char*)&Vsm[cur][0];

        // ---- QK^T (swapped): st0 = S^T[kk 0..31][q], st1 = S^T[kk 32..63][q]
        f32x16 st0, st1;
#pragma unroll
        for (int s = 0; s < 4; ++s) {
            int r0 = ql, r1 = 32 + ql;
            int byt = (s * 32 + hi * 16) ^ ((r0 & 7) << 4);  // (r1&7)==(r0&7)
            f16x8 k0 = *(const f16x8*)(Kb + r0 * 128 + byt);
            f16x8 k1 = *(const f16x8*)(Kb + r1 * 128 + byt);
            if (s == 0) {
                st0 = __builtin_amdgcn_mfma_f32_32x32x16_f16(k0, qb[0], (f32x16)0.f, 0, 0, 0);
                st1 = __builtin_amdgcn_mfma_f32_32x32x16_f16(k1, qb[0], (f32x16)0.f, 0, 0, 0);
            } else {
                st0 = __builtin_amdgcn_mfma_f32_32x32x16_f16(k0, qb[s], st0, 0, 0, 0);
                st1 = __builtin_amdgcn_mfma_f32_32x32x16_f16(k1, qb[s], st1, 0, 0, 0);
            }
        }

        // ---- lane-local online softmax (q = lane&31; this lane + lane^32 hold the row)
        float mx = st0[0];
#pragma unroll
        for (int r = 1; r < 16; ++r) mx = fmaxf(mx, st0[r]);
#pragma unroll
        for (int r = 0; r < 16; ++r) mx = fmaxf(mx, st1[r]);
        mx = fmaxf(mx, __shfl_xor(mx, 32, 64));
        float mn = fmaxf(mraw, mx);
        float al = exp2f((mraw - mn) * SC);
        mraw = mn;
        float msc = mn * SC;
        float ps = 0.f;
#pragma unroll
        for (int r = 0; r < 16; ++r) {
            float p = exp2f(fmaf(st0[r], SC, -msc));
            st0[r] = p;
            ps += p;
        }
#pragma unroll
        for (int r = 0; r < 16; ++r) {
            float p = exp2f(fmaf(st1[r], SC, -msc));
            st1[r] = p;
            ps += p;
        }
        ps += __shfl_xor(ps, 32, 64);
        lsum = lsum * al + ps;
        o0 *= al;
        o1 *= al;

        // ---- PV (swapped): O^T[d][q] += V^T[d][kk] P^T[kk][q], kstep s covers kk=16s..16s+15
#pragma unroll
        for (int s = 0; s < 4; ++s) {
            const int s1 = s & 1;
            // pack this lane's 8 P values (rows 16*s1 + {0..3}+8*... per C-layout) to f16x2 words
            float p0, p1, p2, p3, p4, p5, p6, p7;
            if (s < 2) {
                p0 = st0[8 * s1 + 0]; p1 = st0[8 * s1 + 1]; p2 = st0[8 * s1 + 2]; p3 = st0[8 * s1 + 3];
                p4 = st0[8 * s1 + 4]; p5 = st0[8 * s1 + 5]; p6 = st0[8 * s1 + 6]; p7 = st0[8 * s1 + 7];
            } else {
                p0 = st1[8 * s1 + 0]; p1 = st1[8 * s1 + 1]; p2 = st1[8 * s1 + 2]; p3 = st1[8 * s1 + 3];
                p4 = st1[8 * s1 + 4]; p5 = st1[8 * s1 + 5]; p6 = st1[8 * s1 + 6]; p7 = st1[8 * s1 + 7];
            }
            unsigned c0 = pk2(p0, p1), c1 = pk2(p2, p3);
            unsigned c2 = pk2(p4, p5), c3 = pk2(p6, p7);
            // cross-half exchange: hi=0 lane needs partner's c0,c1; hi=1 needs partner's c2,c3
            unsigned y0 = __shfl_xor(hi ? c0 : c2, 32, 64);
            unsigned y1 = __shfl_xor(hi ? c1 : c3, 32, 64);
            unsigned w0 = hi ? y0 : c0;
            unsigned w1 = hi ? y1 : c1;
            unsigned w2 = hi ? c2 : y0;
            unsigned w3 = hi ? c3 : y1;
            u32x4 pw = {w0, w1, w2, w3};
            f16x8 pf = __builtin_bit_cast(f16x8, pw);
#pragma unroll
            for (int db = 0; db < 2; ++db) {
                int row = db * 32 + ql;
                int byt = (s * 32 + hi * 16) ^ ((row & 7) << 4);
                f16x8 vf = *(const f16x8*)(Vb + row * 128 + byt);
                if (db == 0)
                    o0 = __builtin_amdgcn_mfma_f32_32x32x16_f16(vf, pf, o0, 0, 0, 0);
                else
                    o1 = __builtin_amdgcn_mfma_f32_32x32x16_f16(vf, pf, o1, 0, 0, 0);
            }
        }
        __syncthreads();
        cur ^= 1;
    }

    // ---- epilogue: O^T -> LDS (swizzled transpose) -> coalesced AO[s][h*64+d] f16
    float inv = 1.0f / lsum;
    char* obase = (char*)&Ksm[0][0] + wave * 4096;  // 4 KB per wave (Ksm is dead)
#pragma unroll
    for (int db = 0; db < 2; ++db)
#pragma unroll
        for (int r = 0; r < 16; ++r) {
            int d = db * 32 + (r & 3) + 8 * (r >> 2) + 4 * hi;
            float v = (db == 0 ? o0[r] : o1[r]) * inv;
            *(f16*)(obase + ql * 128 + ((2 * d) ^ ((ql & 7) << 4))) = (f16)v;
        }
    __syncthreads();
    const int rl = lane >> 1, c4 = (lane & 1) * 4;
#pragma unroll
    for (int i = 0; i < 4; ++i) {
        f16x8 ov = *(const f16x8*)(obase + rl * 128 + (((c4 + i) * 16) ^ ((rl & 7) << 4)));
        *(f16x8*)&AO[(b * 1024 + q0 + rl) * 1024 + h * 64 + (c4 + i) * 8] = ov;
    }
}

// ---------------------------------------------------------------- launch
extern "C" void kernel_launch(void* const* d_in, const int* in_sizes, int n_in,
                              void* d_out, int out_size, void* d_ws, size_t ws_size,
                              hipStream_t stream) {
    const float* qkv = (const float*)d_in[0];
    const float* w_in = (const float*)d_in[1];
    const float* b_in = (const float*)d_in[2];
    const float* w_out = (const float*)d_in[3];
    const float* b_out = (const float*)d_in[4];
    float* out = (float*)d_out;

    f16* Xh = (f16*)d_ws;            // 8192*1024
    f16* Wih = Xh + 8388608;         // 3072*1024
    f16* Woh = Wih + 3145728;        // 1024*1024
    f16* Qw = Woh + 1048576;         // [8][16][1024][64]
    f16* Kw = Qw + 8388608;          // [8][16][1024][64]
    f16* Vtw = Kw + 8388608;         // [8][16][64][1024]
    f16* AO = Xh;

    cvt_kernel<<<2048, 256, 0, stream>>>(qkv, Xh, 8388608 / 4);
    cvt_kernel<<<1024, 256, 0, stream>>>(w_in, Wih, 3145728 / 4);
    cvt_kernel<<<512, 256, 0, stream>>>(w_out, Woh, 1048576 / 4);

    gemm_bt<0><<<dim3(24, 64), 256, 0, stream>>>(Xh, Wih, b_in, nullptr, Qw, Kw, Vtw);
    attn_kernel<<<dim3(8, 16, 8), 256, 0, stream>>>(Qw, Kw, Vtw, AO);
    gemm_bt<1><<<dim3(8, 64), 256, 0, stream>>>(AO, Woh, b_out, out, nullptr, nullptr, nullptr);
}